// Round 8
// baseline (153.684 us; speedup 1.0000x reference)
//
#include <hip/hip_runtime.h>
#include <math.h>

// Tropical (max-plus) matmul: y[b,o] = max_i (x[b,i] + W[o,i])
// x: [512,1024] f32, W: [1024,1024] f32 (K-innermost), y: [512,1024] f32.
//
// Round-8: k-pair-outer / m-inner, acc-forced residency, zero LDS.
//   r7 failure: compiler dropped the register-resident W-chunk (VGPR=32!)
//   and re-loaded it per m -> ~1056 VMEM insts/wave -> VMEM-issue-bound.
//   Fix: the ONLY long-lived register state is acc[16] (accumulators can't
//   be re-materialized, compiler must keep them). Per k-pair iteration:
//     - 1 coalesced global_load_dwordx2 of wT[kp][n0+lane] (prefetch 1 ahead,
//       vmcnt is in-order so the wait hides under the previous VALU run);
//     - x slice xP[kp][m0..m0+15] (128 B, wave-uniform address pinned with
//       readfirstlane) -> 2x s_load_dwordx16 into SGPRs, DOUBLE-BUFFERED:
//       p+1's loads issue before p's 32-VALU run, drain lands after cover;
//     - 16x (v_pk_add_f32 (sgpr-pair src) + v_max3_f32).
//   Per wave: 512 VALU vs 48 VMEM + 32 SMEM (r7: ~1056 VMEM).
// Split-K: 32 slices -> part (64 MB, L3-resident) -> 32-deep reduce.

#define MDIM 512
#define NDIM 1024
#define KDIM 1024
#define KP2  (KDIM / 2)   // 512 k-pairs
#define NSLICE 32         // K split: 32 chunks of 32 floats (16 pairs)
#define KCH 16            // k-pairs per chunk
#define MB 16             // m-rows per wave

typedef float v2f __attribute__((ext_vector_type(2)));

// pair-transpose: in = [R][2C] floats viewed as [R][C] v2f; out = [C][R] v2f.
// out[c][r] = {in[r][2c], in[r][2c+1]}   (verified r6/r7, absmax 0)
__global__ __launch_bounds__(256)
void pair_transpose(const v2f* __restrict__ in, v2f* __restrict__ out,
                    int R, int C) {
    __shared__ v2f t[32][33];
    const int tx = threadIdx.x & 31, ty = threadIdx.x >> 5;   // 32x8
    const int c0 = blockIdx.x * 32, r0 = blockIdx.y * 32;
#pragma unroll
    for (int j = 0; j < 4; ++j)
        t[ty + 8 * j][tx] = in[(size_t)(r0 + ty + 8 * j) * C + c0 + tx];
    __syncthreads();
#pragma unroll
    for (int j = 0; j < 4; ++j)
        out[(size_t)(c0 + ty + 8 * j) * R + r0 + tx] = t[tx][ty + 8 * j];
}

// partial: one wave = 16 m x 64 n over one 32-k chunk.
__global__ __launch_bounds__(256, 8)
void tropical_partial(const v2f* __restrict__ xP,   // [KP2][MDIM] pair-major
                      const v2f* __restrict__ wT,   // [KP2][NDIM] pair-major
                      float* __restrict__ part) {
    const int lane = threadIdx.x & 63;
    const int wid  = __builtin_amdgcn_readfirstlane(threadIdx.x >> 6);
    const int task = blockIdx.x * 4 + wid;          // [slice(5)][nb(4)][mb(5)]
    const int mb    = task & 31;                    // mb fastest: block's 4
    const int nb    = (task >> 5) & 15;             //  waves share wT slice
    const int slice = task >> 9;
    const int m0 = mb * MB, n0 = nb * 64, kp0 = slice * KCH;

    const v2f* wcol = wT + (size_t)kp0 * NDIM + n0 + lane;  // per-lane coalesced
    const v2f* xrow = xP + (size_t)kp0 * MDIM + m0;         // wave-uniform

    float acc[MB];
#pragma unroll
    for (int i = 0; i < MB; ++i) acc[i] = -INFINITY;

    // prologue: w pair for p=0, x slice for p=0 (SGPR buffer A)
    v2f wc = wcol[0];
    v2f xa[MB], xb[MB];
#pragma unroll
    for (int i = 0; i < MB; ++i) xa[i] = xrow[i];

#pragma unroll
    for (int p = 0; p < KCH; p += 2) {
        // issue p+1's loads (SGPR buffer B + next w) before p's VALU run
        v2f wn = wcol[(size_t)(p + 1) * NDIM];
#pragma unroll
        for (int i = 0; i < MB; ++i) xb[i] = xrow[(size_t)(p + 1) * MDIM + i];
        // compute p from buffer A
#pragma unroll
        for (int i = 0; i < MB; ++i) {
            const v2f s = wc + xa[i];                       // v_pk_add_f32
            acc[i] = fmaxf(fmaxf(acc[i], s.x), s.y);        // v_max3_f32
        }
        // issue p+2's loads (buffer A) before p+1's VALU run
        v2f w2 = wc;
        if (p + 2 < KCH) {
            w2 = wcol[(size_t)(p + 2) * NDIM];
#pragma unroll
            for (int i = 0; i < MB; ++i) xa[i] = xrow[(size_t)(p + 2) * MDIM + i];
        }
        // compute p+1 from buffer B
#pragma unroll
        for (int i = 0; i < MB; ++i) {
            const v2f s = wn + xb[i];
            acc[i] = fmaxf(fmaxf(acc[i], s.x), s.y);
        }
        wc = w2;
    }

    // epilogue: per m, wave writes 64 contiguous floats (256 B) -- full lines
    float* dst = part + (size_t)slice * (MDIM * NDIM)
                      + (size_t)m0 * NDIM + n0 + lane;
#pragma unroll
    for (int i = 0; i < MB; ++i)
        dst[(size_t)i * NDIM] = acc[i];
}

__global__ __launch_bounds__(256)
void tropical_reduce(const float* __restrict__ ws, float* __restrict__ out,
                     int KS) {
    const int i = blockIdx.x * 256 + threadIdx.x;    // float4 index (exact grid)
    const int stride = MDIM * NDIM / 4;
    const float4* w4 = (const float4*)ws;
    float4 m = w4[i];
#pragma unroll 8
    for (int s = 1; s < KS; ++s) {
        const float4 v = w4[(size_t)s * stride + i];
        m.x = fmaxf(m.x, v.x); m.y = fmaxf(m.y, v.y);
        m.z = fmaxf(m.z, v.z); m.w = fmaxf(m.w, v.w);
    }
    ((float4*)out)[i] = m;
}

// correctness-only fallback if workspace is too small
__global__ __launch_bounds__(256)
void tropical_naive(const float* __restrict__ x, const float* __restrict__ W,
                    float* __restrict__ out) {
    const int idx = blockIdx.x * 256 + threadIdx.x;
    const int b = idx >> 10, n = idx & 1023;
    const float4* xr = (const float4*)(x + (size_t)b * KDIM);
    const float4* wr = (const float4*)(W + (size_t)n * KDIM);
    float m = -INFINITY;
    for (int k = 0; k < KDIM / 4; ++k) {
        const float4 a = xr[k], w = wr[k];
        m = fmaxf(m, fmaxf(fmaxf(a.x + w.x, a.y + w.y),
                           fmaxf(a.z + w.z, a.w + w.w)));
    }
    out[idx] = m;
}

extern "C" void kernel_launch(void* const* d_in, const int* in_sizes, int n_in,
                              void* d_out, int out_size, void* d_ws, size_t ws_size,
                              hipStream_t stream) {
    const float* x = (const float*)d_in[0];
    const float* W = (const float*)d_in[1];
    float* out = (float*)d_out;

    const size_t xPsz  = (size_t)KP2 * MDIM * sizeof(v2f);    // 2 MB
    const size_t wTsz  = (size_t)KP2 * NDIM * sizeof(v2f);    // 4 MB
    const size_t slice = (size_t)MDIM * NDIM * sizeof(float); // 2 MB
    const size_t need  = xPsz + wTsz + (size_t)NSLICE * slice; // 70 MB

    if (need > ws_size) {
        tropical_naive<<<MDIM * NDIM / 256, 256, 0, stream>>>(x, W, out);
        return;
    }

    v2f*   xP   = (v2f*)d_ws;
    v2f*   wT   = (v2f*)((char*)d_ws + xPsz);
    float* part = (float*)((char*)d_ws + xPsz + wTsz);

    // x: [512][512] v2f -> xP [512][512];  W: [1024][512] v2f -> wT [512][1024]
    pair_transpose<<<dim3(KP2 / 32, MDIM / 32), 256, 0, stream>>>(
        (const v2f*)x, xP, MDIM, KP2);
    pair_transpose<<<dim3(KP2 / 32, NDIM / 32), 256, 0, stream>>>(
        (const v2f*)W, wT, NDIM, KP2);

    // 16384 wave-tasks = 4096 blocks x 4 waves
    tropical_partial<<<4096, 256, 0, stream>>>(xP, wT, part);

    tropical_reduce<<<MDIM * NDIM / 4 / 256, 256, 0, stream>>>(part, out, NSLICE);
}

// Round 9
// 86.588 us; speedup vs baseline: 1.7749x; 1.7749x over previous
//
#include <hip/hip_runtime.h>
#include <math.h>

// Tropical (max-plus) matmul: y[b,o] = max_i (x[b,i] + W[o,i])
// x: [512,1024] f32, W: [1024,1024] f32 (K-innermost), y: [512,1024] f32.
//
// Round-9: DS-issue-bound diagnosis of the proven r0 structure (4x4 tile =
// 2 B/op LDS traffic = ~46us DS-pipe issue/CU ~= its 40us). Fix the ratio,
// keep the compiler-friendly shape, keep occupancy:
//  - 128x64 block tile, 256 thr, TM=8 x TN=4  -> 1.5 B/op (DS floor ~15us);
//    acc=32 VGPR, total ~100 -> 4 waves/SIMD (r2's 8x8 hit 256 VGPR, 1 w/SIMD).
//  - single-buffer LDS 25 KB -> 4 blocks/CU; KS=16 -> 1024 blocks = 4/CU.
//  - k-pair-interleaved LDS feeds v_pk_add_f32 + v_max3_f32 (1 inst/elem-op).
//  - A-frag: 4x ds_read_b128, 2-addr 2-way bank alias (free, m136).
//    B-frag: fragmented ownership n = tx+16j -> 4x ds_read_b64 at 16 distinct
//    banks (conflict-free; same DS-issue cost as 2x b128).
//  - zero transposes; pair-interleave happens in the staging ds_writes.
// Split-K: 64 tiles x KS=16 -> part (32 MB, L3-resident) -> 16-deep reduce.

#define MDIM 512
#define NDIM 1024
#define KDIM 1024

#define BM 128
#define BN 64
#define BK 32
#define KPR (BK / 2)        // 16 k-pair rows
#define RA 260              // floats per A kp-row: 2*BM + 4 pad (1040 B, 16B-aligned)
#define RB 132              // floats per B kp-row: 2*BN + 4 pad (528 B, 16B-aligned)
#define NTHREADS 256
#define KS_DEF 16

typedef float v2f __attribute__((ext_vector_type(2)));

__global__ __launch_bounds__(NTHREADS, 4)
void tropical_partial(const float* __restrict__ x, const float* __restrict__ W,
                      float* __restrict__ ws, int KC) {
    __shared__ float As[KPR * RA];   // 16640 B, As[p][2m+e]
    __shared__ float Bs[KPR * RB];   //  8448 B, Bs[p][2n+e]

    const int tiles_n = NDIM / BN;                  // 16
    const int tm0 = (blockIdx.x / tiles_n) * BM;
    const int tn0 = (blockIdx.x % tiles_n) * BN;
    const int k0  = blockIdx.y * KC;

    const int tid = threadIdx.x;
    // staging maps
    const int smA = tid >> 1;            // 0..127; 2 thr/row, 16 floats each
    const int skA = (tid & 1) * 16;
    const int smB = tid >> 2;            // 0..63;  4 thr/row, 8 floats each
    const int skB = (tid & 3) * 8;
    // compute map: m = 8*ty + i, n = tx + 16*j
    const int tx = tid & 15;
    const int ty = tid >> 4;             // 0..15

    float acc[8][4];
#pragma unroll
    for (int i = 0; i < 8; ++i)
#pragma unroll
        for (int j = 0; j < 4; ++j) acc[i][j] = -INFINITY;

    const float* xrow = x + (size_t)(tm0 + smA) * KDIM + skA;
    const float* wrow = W + (size_t)(tn0 + smB) * KDIM + skB;

    const int nt = KC / BK;
    for (int t = 0; t < nt; ++t) {
        const int kb = k0 + t * BK;
        // global loads issued before the barrier (in flight during wait)
        float4 a[4], b[2];
#pragma unroll
        for (int j2 = 0; j2 < 4; ++j2)
            a[j2] = *(const float4*)(xrow + kb + 4 * j2);
#pragma unroll
        for (int j2 = 0; j2 < 2; ++j2)
            b[j2] = *(const float4*)(wrow + kb + 4 * j2);

        __syncthreads();   // previous iter's frag reads done before overwrite
        // pair-interleaved stores: float4 {k..k+3} -> kp rows p, p+1
        {
            const int pA = skA >> 1;     // 0 or 8
#pragma unroll
            for (int j2 = 0; j2 < 4; ++j2) {
                v2f lo, hi;
                lo.x = a[j2].x; lo.y = a[j2].y;
                hi.x = a[j2].z; hi.y = a[j2].w;
                *(v2f*)&As[(pA + 2 * j2) * RA + 2 * smA]     = lo;
                *(v2f*)&As[(pA + 2 * j2 + 1) * RA + 2 * smA] = hi;
            }
            const int pB = skB >> 1;     // 0,4,8,12
#pragma unroll
            for (int j2 = 0; j2 < 2; ++j2) {
                v2f lo, hi;
                lo.x = b[j2].x; lo.y = b[j2].y;
                hi.x = b[j2].z; hi.y = b[j2].w;
                *(v2f*)&Bs[(pB + 2 * j2) * RB + 2 * smB]     = lo;
                *(v2f*)&Bs[(pB + 2 * j2 + 1) * RB + 2 * smB] = hi;
            }
        }
        __syncthreads();

        // compute: per kp, A = 4x b128 (m=8ty..8ty+7), B = 4x b64 (n=tx+16j)
#pragma unroll
        for (int kp = 0; kp < KPR; ++kp) {
            const float* ra = As + kp * RA;
            const float* rb = Bs + kp * RB;
            float4 af[4];
#pragma unroll
            for (int q = 0; q < 4; ++q)
                af[q] = *(const float4*)(ra + 16 * ty + 4 * q);
            v2f bn[4];
#pragma unroll
            for (int j = 0; j < 4; ++j)
                bn[j] = *(const v2f*)(rb + 2 * (tx + 16 * j));
            v2f am[8];
#pragma unroll
            for (int q = 0; q < 4; ++q) {
                am[2 * q].x     = af[q].x; am[2 * q].y     = af[q].y;
                am[2 * q + 1].x = af[q].z; am[2 * q + 1].y = af[q].w;
            }
#pragma unroll
            for (int i = 0; i < 8; ++i)
#pragma unroll
                for (int j = 0; j < 4; ++j) {
                    const v2f s = am[i] + bn[j];                    // v_pk_add_f32
                    acc[i][j] = fmaxf(fmaxf(acc[i][j], s.x), s.y);  // v_max3_f32
                }
        }
    }

    // epilogue: lane owns rows tm0+8ty+i, cols tn0+tx+16j
    float* wsl = ws + (size_t)blockIdx.y * (MDIM * NDIM);
#pragma unroll
    for (int i = 0; i < 8; ++i) {
        float* r = &wsl[(size_t)(tm0 + 8 * ty + i) * NDIM + tn0 + tx];
#pragma unroll
        for (int j = 0; j < 4; ++j)
            r[16 * j] = acc[i][j];
    }
}

__global__ __launch_bounds__(256)
void tropical_reduce(const float* __restrict__ ws, float* __restrict__ out,
                     int KS) {
    const int i = blockIdx.x * 256 + threadIdx.x;    // float4 index (exact grid)
    const int stride = MDIM * NDIM / 4;
    const float4* w4 = (const float4*)ws;
    float4 m = w4[i];
#pragma unroll 8
    for (int s = 1; s < KS; ++s) {
        const float4 v = w4[(size_t)s * stride + i];
        m.x = fmaxf(m.x, v.x); m.y = fmaxf(m.y, v.y);
        m.z = fmaxf(m.z, v.z); m.w = fmaxf(m.w, v.w);
    }
    ((float4*)out)[i] = m;
}

// correctness-only fallback if workspace is too small
__global__ __launch_bounds__(256)
void tropical_naive(const float* __restrict__ x, const float* __restrict__ W,
                    float* __restrict__ out) {
    const int idx = blockIdx.x * 256 + threadIdx.x;
    const int b = idx >> 10, n = idx & 1023;
    const float4* xr = (const float4*)(x + (size_t)b * KDIM);
    const float4* wr = (const float4*)(W + (size_t)n * KDIM);
    float m = -INFINITY;
    for (int k = 0; k < KDIM / 4; ++k) {
        const float4 a = xr[k], w = wr[k];
        m = fmaxf(m, fmaxf(fmaxf(a.x + w.x, a.y + w.y),
                           fmaxf(a.z + w.z, a.w + w.w)));
    }
    out[idx] = m;
}

extern "C" void kernel_launch(void* const* d_in, const int* in_sizes, int n_in,
                              void* d_out, int out_size, void* d_ws, size_t ws_size,
                              hipStream_t stream) {
    const float* x = (const float*)d_in[0];
    const float* W = (const float*)d_in[1];
    float* out = (float*)d_out;
    float* ws  = (float*)d_ws;

    const size_t slice = (size_t)MDIM * NDIM * sizeof(float);  // 2 MB per slice
    int KS = KS_DEF;                                 // 16 -> 1024 blocks = 4/CU
    while (KS > 1 && (size_t)KS * slice > ws_size) KS >>= 1;

    const int ntiles = (MDIM / BM) * (NDIM / BN);    // 64

    if (slice > ws_size) {
        tropical_naive<<<MDIM * NDIM / 256, 256, 0, stream>>>(x, W, out);
        return;
    }

    const int KC = KDIM / KS;                        // 64 at KS=16
    tropical_partial<<<dim3(ntiles, KS), NTHREADS, 0, stream>>>(x, W, ws, KC);

    tropical_reduce<<<MDIM * NDIM / 4 / 256, 256, 0, stream>>>(ws, out, KS);
}